// Round 7
// baseline (611.262 us; speedup 1.0000x reference)
//
#include <hip/hip_runtime.h>
#include <hip/hip_fp16.h>
#include <cstdint>

#define HIDDEN 128
#define MTOT 16
#define NBUCK 8

typedef float vfloat4 __attribute__((ext_vector_type(4)));

// 12-byte edge record: e, (dst<<16)|src, cutoff bits
struct __align__(4) Rec {
  uint32_t e;
  uint32_t sd;
  uint32_t cut;
};

// ---------------------------------------------------------------------------
// Zero d_out + bucket cursors (cursors padded to one 64B line each).
// ---------------------------------------------------------------------------
__global__ __launch_bounds__(256) void setup_kernel(float4* __restrict__ out,
                                                    int n4,
                                                    uint32_t* __restrict__ cursors) {
  int i = blockIdx.x * 256 + threadIdx.x;
  if (i < NBUCK) cursors[i * 16] = 0;
  int stride = gridDim.x * 256;
  float4 z = {0.f, 0.f, 0.f, 0.f};
  for (; i < n4; i += stride) out[i] = z;
}

// ---------------------------------------------------------------------------
// Bucket edges by dst/div into NBUCK buckets. LDS histogram -> one global
// cursor reservation per (block,bucket) -> compact record write.
// ---------------------------------------------------------------------------
__global__ __launch_bounds__(256) void bucket_kernel(
    const int* __restrict__ ei, const float* __restrict__ cutoff,
    int E, uint32_t div, uint32_t* __restrict__ cursors,
    Rec* __restrict__ elist, int ecap) {
  __shared__ uint32_t lcnt[NBUCK];
  __shared__ uint32_t lbase[NBUCK];
  const int tid = threadIdx.x;
  const int e = blockIdx.x * 256 + tid;
  if (tid < NBUCK) lcnt[tid] = 0;
  __syncthreads();

  uint32_t src = 0, dst = 0, b = 0, lr = 0;
  float c = 0.f;
  const bool valid = e < E;
  if (valid) {
    src = (uint32_t)ei[e];
    dst = (uint32_t)ei[E + e];
    c = cutoff[e];
    b = dst / div;
    lr = atomicAdd(&lcnt[b], 1u);
  }
  __syncthreads();
  if (tid < NBUCK) lbase[tid] = atomicAdd(&cursors[tid * 16], lcnt[tid]);
  __syncthreads();
  if (valid) {
    Rec r;
    r.e = (uint32_t)e;
    r.sd = src | (dst << 16);
    r.cut = __float_as_uint(c);
    elist[(size_t)b * ecap + lbase[b] + lr] = r;
  }
}

// ---------------------------------------------------------------------------
// q/k projection, fp16 output. W in LDS, float4-preserving XOR swizzle.
// 8-row unroll: one ds_read_b128 feeds 32 FMAs.
// ---------------------------------------------------------------------------
__global__ __launch_bounds__(256) void proj_kernel(
    const float* __restrict__ x, const float* __restrict__ W,
    __half* __restrict__ out, int n_rows, float scale) {
  __shared__ float sW[128 * 128];  // 64 KB, swizzled
  for (int i = threadIdx.x; i < 128 * 128; i += 256) {
    int j = i >> 7, d = i & 127;
    sW[j * 128 + (d ^ ((j & 7) << 2))] = W[i] * scale;
  }
  __syncthreads();

  const int col = threadIdx.x & 127;
  const int g   = threadIdx.x >> 7;
  const int sx  = (col & 7) << 2;
  const float* sWc = sW + col * 128;

  const int row0 = blockIdx.x * 64;
#pragma unroll 1
  for (int m = 0; m < 4; ++m) {
    int r0 = row0 + g * 8 + m * 16;
    if (r0 >= n_rows) break;
    const float4* x4 = (const float4*)(x + (size_t)r0 * HIDDEN);
    if (r0 + 7 < n_rows) {
      float a0 = 0.f, a1 = 0.f, a2 = 0.f, a3 = 0.f;
      float a4 = 0.f, a5 = 0.f, a6 = 0.f, a7 = 0.f;
#pragma unroll
      for (int d4 = 0; d4 < 32; ++d4) {
        float4 w4 = *(const float4*)(sWc + ((d4 << 2) ^ sx));
        float4 xv0 = x4[d4];
        float4 xv1 = x4[32 + d4];
        float4 xv2 = x4[64 + d4];
        float4 xv3 = x4[96 + d4];
        float4 xv4 = x4[128 + d4];
        float4 xv5 = x4[160 + d4];
        float4 xv6 = x4[192 + d4];
        float4 xv7 = x4[224 + d4];
        a0 += xv0.x * w4.x + xv0.y * w4.y + xv0.z * w4.z + xv0.w * w4.w;
        a1 += xv1.x * w4.x + xv1.y * w4.y + xv1.z * w4.z + xv1.w * w4.w;
        a2 += xv2.x * w4.x + xv2.y * w4.y + xv2.z * w4.z + xv2.w * w4.w;
        a3 += xv3.x * w4.x + xv3.y * w4.y + xv3.z * w4.z + xv3.w * w4.w;
        a4 += xv4.x * w4.x + xv4.y * w4.y + xv4.z * w4.z + xv4.w * w4.w;
        a5 += xv5.x * w4.x + xv5.y * w4.y + xv5.z * w4.z + xv5.w * w4.w;
        a6 += xv6.x * w4.x + xv6.y * w4.y + xv6.z * w4.z + xv6.w * w4.w;
        a7 += xv7.x * w4.x + xv7.y * w4.y + xv7.z * w4.z + xv7.w * w4.w;
      }
      out[(size_t)(r0 + 0) * HIDDEN + col] = __float2half(a0);
      out[(size_t)(r0 + 1) * HIDDEN + col] = __float2half(a1);
      out[(size_t)(r0 + 2) * HIDDEN + col] = __float2half(a2);
      out[(size_t)(r0 + 3) * HIDDEN + col] = __float2half(a3);
      out[(size_t)(r0 + 4) * HIDDEN + col] = __float2half(a4);
      out[(size_t)(r0 + 5) * HIDDEN + col] = __float2half(a5);
      out[(size_t)(r0 + 6) * HIDDEN + col] = __float2half(a6);
      out[(size_t)(r0 + 7) * HIDDEN + col] = __float2half(a7);
    } else {
      for (int r = r0; r < n_rows; ++r) {
        const float4* xr = (const float4*)(x + (size_t)r * HIDDEN);
        float a = 0.f;
        for (int d4 = 0; d4 < 32; ++d4) {
          float4 w4 = *(const float4*)(sWc + ((d4 << 2) ^ sx));
          float4 xv = xr[d4];
          a += xv.x * w4.x + xv.y * w4.y + xv.z * w4.z + xv.w * w4.w;
        }
        out[(size_t)r * HIDDEN + col] = __float2half(a);
      }
    }
  }
}

// ---------------------------------------------------------------------------
// Edge kernel, dst-bucketed: blocks with blockIdx%8 == b process only bucket
// b's edges (round-robin dispatch puts them on one XCD). q gathers then hit a
// 1.6MB dst-slice resident in that XCD's L2, and output atomics are XCD-local.
// 32 lanes per edge; records carry e/src/dst/cutoff (coalesced 12B read).
// ---------------------------------------------------------------------------
__global__ __launch_bounds__(256) void edge_kernel(
    const __half* __restrict__ q, const __half* __restrict__ k,
    const float* __restrict__ w_ij, const float* __restrict__ sph,
    const uint32_t* __restrict__ cursors, const Rec* __restrict__ elist,
    int ecap, float* __restrict__ out, int groups_per_bucket) {
  const int bucket   = blockIdx.x & (NBUCK - 1);
  const int gslot    = (blockIdx.x >> 3) * 8 + (threadIdx.x >> 5);
  const int lane     = threadIdx.x & 31;
  const int halfbase = threadIdx.x & 32;
  // m -> head: m0->h0, m1..3->h1, m4..8->h2, m9..15->h3
  const int h_for_m  = (lane >= 1) + (lane >= 4) + (lane >= 9);
  const int srcLane  = halfbase + (h_for_m << 3);

  const int count = (int)cursors[bucket * 16];
  const Rec* bl = elist + (size_t)bucket * ecap;

  for (int i = gslot; i < count; i += groups_per_bucket) {
    Rec r = bl[i];
    const uint32_t e = r.e;
    const uint32_t src = r.sd & 0xffffu;
    const uint32_t dst = r.sd >> 16;
    const float cut = __uint_as_float(r.cut);

    vfloat4 w4 = __builtin_nontemporal_load(
        (const vfloat4*)(w_ij + (size_t)e * HIDDEN) + lane);
    union { uint2 u; __half2 h2[2]; } qa, ka;
    qa.u = *((const uint2*)(q + (size_t)dst * HIDDEN) + lane);
    ka.u = *((const uint2*)(k + (size_t)src * HIDDEN) + lane);
    float2 q01 = __half22float2(qa.h2[0]);
    float2 q23 = __half22float2(qa.h2[1]);
    float2 k01 = __half22float2(ka.h2[0]);
    float2 k23 = __half22float2(ka.h2[1]);
    float p = q01.x * w4.x * k01.x + q01.y * w4.y * k01.y +
              q23.x * w4.z * k23.x + q23.y * w4.w * k23.y;
    p += __shfl_xor(p, 1);
    p += __shfl_xor(p, 2);
    p += __shfl_xor(p, 4);
    float alpha = p * cut;
    float am = __shfl(alpha, srcLane);
    if (lane < 16) {
      float s = __builtin_nontemporal_load(sph + (size_t)e * MTOT + lane);
      atomicAdd(out + (size_t)dst * MTOT + lane, am * s);
    }
  }
}

extern "C" void kernel_launch(void* const* d_in, const int* in_sizes, int n_in,
                              void* d_out, int out_size, void* d_ws, size_t ws_size,
                              hipStream_t stream) {
  // inputs: chi, sph_ij, x, w_ij, edge_index, cutoff, Wq, Wk
  const float* sph    = (const float*)d_in[1];
  const float* x      = (const float*)d_in[2];
  const float* w_ij   = (const float*)d_in[3];
  const int*   ei     = (const int*)d_in[4];
  const float* cutoff = (const float*)d_in[5];
  const float* Wq     = (const float*)d_in[6];
  const float* Wk     = (const float*)d_in[7];
  float* out = (float*)d_out;

  const int n_nodes = in_sizes[0] / MTOT;  // chi is [N, 16]
  const int E       = in_sizes[5];         // cutoff is [E, 1]

  // ws layout: q fp16 (12.8MB) | k fp16 (12.8MB) | cursors (512B) | elist
  __half* q = (__half*)d_ws;
  __half* k = q + (size_t)n_nodes * HIDDEN;
  uint32_t* cursors = (uint32_t*)(k + (size_t)n_nodes * HIDDEN);
  Rec* elist = (Rec*)(cursors + NBUCK * 16);
  const int ecap = E / NBUCK + 4096;       // ~10 sigma slack over E/8

  const int n4 = out_size / 4;
  setup_kernel<<<256, 256, 0, stream>>>((float4*)out, n4, cursors);

  const int pgrid = (n_nodes + 63) / 64;
  const float inv_sqrt_hd = 0.17677669529663687f;  // 1/sqrt(32)
  proj_kernel<<<pgrid, 256, 0, stream>>>(x, Wq, q, n_nodes, inv_sqrt_hd);
  proj_kernel<<<pgrid, 256, 0, stream>>>(x, Wk, k, n_nodes, 1.0f);

  const uint32_t div = (uint32_t)((n_nodes + NBUCK - 1) / NBUCK);  // 6250
  bucket_kernel<<<(E + 255) / 256, 256, 0, stream>>>(ei, cutoff, E, div,
                                                     cursors, elist, ecap);

  const int NB = 20000;  // multiple of 8; 2500 blocks x 8 groups per bucket
  edge_kernel<<<NB, 256, 0, stream>>>(q, k, w_ij, sph, cursors, elist, ecap,
                                      out, NB);
}

// Round 8
// 482.368 us; speedup vs baseline: 1.2672x; 1.2672x over previous
//
#include <hip/hip_runtime.h>
#include <hip/hip_fp16.h>
#include <cstdint>

#define HIDDEN 128
#define MTOT 16

typedef float vfloat4 __attribute__((ext_vector_type(4)));

// ---------------------------------------------------------------------------
// Zero-fill d_out (harness poisons d_out with 0xAA; graph must re-zero).
// ---------------------------------------------------------------------------
__global__ __launch_bounds__(256) void zero_kernel(float4* __restrict__ out,
                                                   int n4) {
  int i = blockIdx.x * 256 + threadIdx.x;
  int stride = gridDim.x * 256;
  float4 z = {0.f, 0.f, 0.f, 0.f};
  for (; i < n4; i += stride) out[i] = z;
}

// ---------------------------------------------------------------------------
// q/k projection, fp16 output. W in LDS, float4-preserving XOR swizzle.
// 8-row unroll: one ds_read_b128 feeds 32 FMAs.
// ---------------------------------------------------------------------------
__global__ __launch_bounds__(256) void proj_kernel(
    const float* __restrict__ x, const float* __restrict__ W,
    __half* __restrict__ out, int n_rows, float scale) {
  __shared__ float sW[128 * 128];  // 64 KB, swizzled
  for (int i = threadIdx.x; i < 128 * 128; i += 256) {
    int j = i >> 7, d = i & 127;
    sW[j * 128 + (d ^ ((j & 7) << 2))] = W[i] * scale;
  }
  __syncthreads();

  const int col = threadIdx.x & 127;
  const int g   = threadIdx.x >> 7;
  const int sx  = (col & 7) << 2;
  const float* sWc = sW + col * 128;

  const int row0 = blockIdx.x * 64;
#pragma unroll 1
  for (int m = 0; m < 4; ++m) {
    int r0 = row0 + g * 8 + m * 16;
    if (r0 >= n_rows) break;
    const float4* x4 = (const float4*)(x + (size_t)r0 * HIDDEN);
    if (r0 + 7 < n_rows) {
      float a0 = 0.f, a1 = 0.f, a2 = 0.f, a3 = 0.f;
      float a4 = 0.f, a5 = 0.f, a6 = 0.f, a7 = 0.f;
#pragma unroll
      for (int d4 = 0; d4 < 32; ++d4) {
        float4 w4 = *(const float4*)(sWc + ((d4 << 2) ^ sx));
        float4 xv0 = x4[d4];
        float4 xv1 = x4[32 + d4];
        float4 xv2 = x4[64 + d4];
        float4 xv3 = x4[96 + d4];
        float4 xv4 = x4[128 + d4];
        float4 xv5 = x4[160 + d4];
        float4 xv6 = x4[192 + d4];
        float4 xv7 = x4[224 + d4];
        a0 += xv0.x * w4.x + xv0.y * w4.y + xv0.z * w4.z + xv0.w * w4.w;
        a1 += xv1.x * w4.x + xv1.y * w4.y + xv1.z * w4.z + xv1.w * w4.w;
        a2 += xv2.x * w4.x + xv2.y * w4.y + xv2.z * w4.z + xv2.w * w4.w;
        a3 += xv3.x * w4.x + xv3.y * w4.y + xv3.z * w4.z + xv3.w * w4.w;
        a4 += xv4.x * w4.x + xv4.y * w4.y + xv4.z * w4.z + xv4.w * w4.w;
        a5 += xv5.x * w4.x + xv5.y * w4.y + xv5.z * w4.z + xv5.w * w4.w;
        a6 += xv6.x * w4.x + xv6.y * w4.y + xv6.z * w4.z + xv6.w * w4.w;
        a7 += xv7.x * w4.x + xv7.y * w4.y + xv7.z * w4.z + xv7.w * w4.w;
      }
      out[(size_t)(r0 + 0) * HIDDEN + col] = __float2half(a0);
      out[(size_t)(r0 + 1) * HIDDEN + col] = __float2half(a1);
      out[(size_t)(r0 + 2) * HIDDEN + col] = __float2half(a2);
      out[(size_t)(r0 + 3) * HIDDEN + col] = __float2half(a3);
      out[(size_t)(r0 + 4) * HIDDEN + col] = __float2half(a4);
      out[(size_t)(r0 + 5) * HIDDEN + col] = __float2half(a5);
      out[(size_t)(r0 + 6) * HIDDEN + col] = __float2half(a6);
      out[(size_t)(r0 + 7) * HIDDEN + col] = __float2half(a7);
    } else {
      for (int r = r0; r < n_rows; ++r) {
        const float4* xr = (const float4*)(x + (size_t)r * HIDDEN);
        float a = 0.f;
        for (int d4 = 0; d4 < 32; ++d4) {
          float4 w4 = *(const float4*)(sWc + ((d4 << 2) ^ sx));
          float4 xv = xr[d4];
          a += xv.x * w4.x + xv.y * w4.y + xv.z * w4.z + xv.w * w4.w;
        }
        out[(size_t)r * HIDDEN + col] = __float2half(a);
      }
    }
  }
}

// ---------------------------------------------------------------------------
// Edge kernel (R4 structure + XCD swizzle + 2-edge unroll).
// - Block-rank swizzle groups adjacent edge windows onto ONE XCD (blocks are
//   dispatched round-robin over 8 XCDs): ei/cutoff/sph cache lines are shared
//   within one L2 instead of replicated across 8.
// - 2-edge unroll: all loads for both edges issued before either compute,
//   doubling memory-level parallelism per wave.
// ---------------------------------------------------------------------------
__global__ __launch_bounds__(256) void edge_kernel(
    const __half* __restrict__ q, const __half* __restrict__ k,
    const float* __restrict__ w_ij, const float* __restrict__ sph,
    const int* __restrict__ ei, const float* __restrict__ cutoff,
    float* __restrict__ out, int E, int ngroups, int nb8) {
  const int rank     = (blockIdx.x & 7) * nb8 + (blockIdx.x >> 3);
  const int gid      = rank * 8 + (threadIdx.x >> 5);
  const int lane     = threadIdx.x & 31;
  const int halfbase = threadIdx.x & 32;
  // m -> head: m0->h0, m1..3->h1, m4..8->h2, m9..15->h3
  const int h_for_m  = (lane >= 1) + (lane >= 4) + (lane >= 9);
  const int srcLane  = halfbase + (h_for_m << 3);

  int e = gid;
  for (; e + ngroups < E; e += 2 * ngroups) {
    const int e2 = e + ngroups;
    // --- issue ALL loads for both edges first ---
    int srcA = __builtin_nontemporal_load(ei + e);
    int dstA = __builtin_nontemporal_load(ei + E + e);
    int srcB = __builtin_nontemporal_load(ei + e2);
    int dstB = __builtin_nontemporal_load(ei + E + e2);
    float cutA = __builtin_nontemporal_load(cutoff + e);
    float cutB = __builtin_nontemporal_load(cutoff + e2);
    vfloat4 wA = __builtin_nontemporal_load(
        (const vfloat4*)(w_ij + (size_t)e * HIDDEN) + lane);
    vfloat4 wB = __builtin_nontemporal_load(
        (const vfloat4*)(w_ij + (size_t)e2 * HIDDEN) + lane);
    union { uint2 u; __half2 h2[2]; } qA, kA, qB, kB;
    qA.u = *((const uint2*)(q + (size_t)dstA * HIDDEN) + lane);
    kA.u = *((const uint2*)(k + (size_t)srcA * HIDDEN) + lane);
    qB.u = *((const uint2*)(q + (size_t)dstB * HIDDEN) + lane);
    kB.u = *((const uint2*)(k + (size_t)srcB * HIDDEN) + lane);

    // --- compute edge A ---
    float2 qa01 = __half22float2(qA.h2[0]);
    float2 qa23 = __half22float2(qA.h2[1]);
    float2 ka01 = __half22float2(kA.h2[0]);
    float2 ka23 = __half22float2(kA.h2[1]);
    float pA = qa01.x * wA.x * ka01.x + qa01.y * wA.y * ka01.y +
               qa23.x * wA.z * ka23.x + qa23.y * wA.w * ka23.y;
    // --- compute edge B ---
    float2 qb01 = __half22float2(qB.h2[0]);
    float2 qb23 = __half22float2(qB.h2[1]);
    float2 kb01 = __half22float2(kB.h2[0]);
    float2 kb23 = __half22float2(kB.h2[1]);
    float pB = qb01.x * wB.x * kb01.x + qb01.y * wB.y * kb01.y +
               qb23.x * wB.z * kb23.x + qb23.y * wB.w * kb23.y;

    pA += __shfl_xor(pA, 1);
    pB += __shfl_xor(pB, 1);
    pA += __shfl_xor(pA, 2);
    pB += __shfl_xor(pB, 2);
    pA += __shfl_xor(pA, 4);
    pB += __shfl_xor(pB, 4);
    float alphaA = pA * cutA;
    float alphaB = pB * cutB;
    float amA = __shfl(alphaA, srcLane);
    float amB = __shfl(alphaB, srcLane);
    if (lane < 16) {
      float sA = __builtin_nontemporal_load(sph + (size_t)e * MTOT + lane);
      float sB = __builtin_nontemporal_load(sph + (size_t)e2 * MTOT + lane);
      atomicAdd(out + (size_t)dstA * MTOT + lane, amA * sA);
      atomicAdd(out + (size_t)dstB * MTOT + lane, amB * sB);
    }
  }
  if (e < E) {  // tail (not taken when E % (2*ngroups) == 0)
    int src = __builtin_nontemporal_load(ei + e);
    int dst = __builtin_nontemporal_load(ei + E + e);
    vfloat4 w4 = __builtin_nontemporal_load(
        (const vfloat4*)(w_ij + (size_t)e * HIDDEN) + lane);
    union { uint2 u; __half2 h2[2]; } qa, ka;
    qa.u = *((const uint2*)(q + (size_t)dst * HIDDEN) + lane);
    ka.u = *((const uint2*)(k + (size_t)src * HIDDEN) + lane);
    float2 q01 = __half22float2(qa.h2[0]);
    float2 q23 = __half22float2(qa.h2[1]);
    float2 k01 = __half22float2(ka.h2[0]);
    float2 k23 = __half22float2(ka.h2[1]);
    float p = q01.x * w4.x * k01.x + q01.y * w4.y * k01.y +
              q23.x * w4.z * k23.x + q23.y * w4.w * k23.y;
    p += __shfl_xor(p, 1);
    p += __shfl_xor(p, 2);
    p += __shfl_xor(p, 4);
    float alpha = p * __builtin_nontemporal_load(cutoff + e);
    float am = __shfl(alpha, srcLane);
    if (lane < 16) {
      float s = __builtin_nontemporal_load(sph + (size_t)e * MTOT + lane);
      atomicAdd(out + (size_t)dst * MTOT + lane, am * s);
    }
  }
}

extern "C" void kernel_launch(void* const* d_in, const int* in_sizes, int n_in,
                              void* d_out, int out_size, void* d_ws, size_t ws_size,
                              hipStream_t stream) {
  // inputs: chi, sph_ij, x, w_ij, edge_index, cutoff, Wq, Wk
  const float* sph    = (const float*)d_in[1];
  const float* x      = (const float*)d_in[2];
  const float* w_ij   = (const float*)d_in[3];
  const int*   ei     = (const int*)d_in[4];
  const float* cutoff = (const float*)d_in[5];
  const float* Wq     = (const float*)d_in[6];
  const float* Wk     = (const float*)d_in[7];
  float* out = (float*)d_out;

  const int n_nodes = in_sizes[0] / MTOT;  // chi is [N, 16]
  const int E       = in_sizes[5];         // cutoff is [E, 1]

  __half* q = (__half*)d_ws;
  __half* k = q + (size_t)n_nodes * HIDDEN;

  const int n4 = out_size / 4;
  zero_kernel<<<256, 256, 0, stream>>>((float4*)out, n4);

  const int pgrid = (n_nodes + 63) / 64;
  const float inv_sqrt_hd = 0.17677669529663687f;  // 1/sqrt(32)
  proj_kernel<<<pgrid, 256, 0, stream>>>(x, Wq, q, n_nodes, inv_sqrt_hd);
  proj_kernel<<<pgrid, 256, 0, stream>>>(x, Wk, k, n_nodes, 1.0f);

  const int NB = 20000;  // multiple of 8; 160000 groups, 10 edges each
  const int ngroups = NB * 8;
  edge_kernel<<<NB, 256, 0, stream>>>(q, k, w_ij, sph, ei, cutoff, out, E,
                                      ngroups, NB / 8);
}